// Round 16
// baseline (83.982 us; speedup 1.0000x reference)
//
#include <hip/hip_runtime.h>
#include <hip/hip_bf16.h>

// Problem constants
#define BATCH 8
#define NN 2048
#define IN_F 256
#define OUT_F 128
#define ALPHA 0.2f

typedef __attribute__((ext_vector_type(8))) short short8v;
typedef __attribute__((ext_vector_type(4))) float f32x4;

// exact RTNE f32 -> bf16 bits (scalar)
static __device__ __forceinline__ unsigned short f2bf(float x) {
    unsigned int u = __float_as_uint(x);
    u = (u + 0x7fffu + ((u >> 16) & 1u)) >> 16;
    return (unsigned short)u;
}

// pack 4 floats -> 4 bf16 (8 B) via v_cvt_pk_bf16_f32 (RTNE, compiler-emitted)
static __device__ __forceinline__ unsigned long long pk4(float a, float b, float c, float d) {
    union { unsigned long long ll; __hip_bfloat162 h2[2]; } u;
    u.h2[0] = __float22bfloat162_rn(make_float2(a, b));
    u.h2[1] = __float22bfloat162_rn(make_float2(c, d));
    return u.ll;
}

// ---------------------------------------------------------------------------
// Kernel 0: weight prep.  (unchanged r15)
// ---------------------------------------------------------------------------
__global__ __launch_bounds__(256) void k_prew(
    const float* __restrict__ W1, const float* __restrict__ W2,
    const float* __restrict__ a,
    unsigned short* __restrict__ Wt, float* __restrict__ w1a1, float* __restrict__ w1a2)
{
    const int t = threadIdx.x;
    const int k8 = blockIdx.x * 8;
#pragma unroll
    for (int q = 0; q < 4; ++q) {
        const int idx = q * 256 + t;
        const int o = idx & 127;
        const int kk = k8 + (idx >> 7);
        const float v = (kk < IN_F) ? W1[kk * OUT_F + o] : W2[(kk - IN_F) * OUT_F + o];
        Wt[(size_t)o * 512 + kk] = f2bf(v);
    }
    if (k8 < IN_F) {
        const int lane = t & 63, w = t >> 6;
#pragma unroll
        for (int u = 0; u < 2; ++u) {
            const int kk = k8 + 2 * w + u;
            const float* wr = W1 + kk * OUT_F;
            float v1 = wr[lane] * a[lane] + wr[lane + 64] * a[lane + 64];
            float v2 = wr[lane] * a[OUT_F + lane] + wr[lane + 64] * a[OUT_F + lane + 64];
#pragma unroll
            for (int off = 32; off; off >>= 1) {
                v1 += __shfl_xor(v1, off);
                v2 += __shfl_xor(v2, off);
            }
            if (lane == 0) { w1a1[kk] = v1; w1a2[kk] = v2; }
        }
    }
}

// ---------------------------------------------------------------------------
// Kernel 1: projections via bf16 MFMA + strided adj->bits sweep tail.
// (unchanged r15 / r9 form)
// ---------------------------------------------------------------------------
#define BM 16

__global__ __launch_bounds__(256) void k_proj(
    const float* __restrict__ h, const float* __restrict__ j,
    const unsigned short* __restrict__ Wt,
    const float* __restrict__ w1a1g, const float* __restrict__ w1a2g,
    const int* __restrict__ adj,
    unsigned short* __restrict__ Vf, float* __restrict__ s1, float* __restrict__ s2,
    unsigned short* __restrict__ bits16)
{
    __shared__ __align__(16) unsigned short X[BM * 512];  // 16 KB, XOR-swizzled

    const int t = threadIdx.x, lane = t & 63, w = t >> 6;
    const int row0 = blockIdx.x * BM;
    const int b = row0 >> 11, n0 = row0 & 2047;

    const float4* wa1v = (const float4*)w1a1g;
    const float4* wa2v = (const float4*)w1a2g;

    const int srow = w * 4 + (lane >> 4);   // this lane's staging row (fixed)
    const int scol = lane & 15;
    const int sswz = (srow & 7) << 4;
    const float* hrow = h + (size_t)(row0 + srow) * IN_F;
    const float* jrow = j + (size_t)(row0 + srow) * IN_F;

    float d1 = 0.f, d2 = 0.f;
#pragma unroll
    for (int q = 0; q < 4; ++q) {
        const int f4 = q * 16 + scol;
        const float4 hv = ((const float4*)hrow)[f4];
        *(unsigned long long*)((char*)X + ((srow * 1024 + f4 * 8) ^ sswz)) =
            pk4(hv.x, hv.y, hv.z, hv.w);
        const float4 a1 = wa1v[f4], a2 = wa2v[f4];
        d1 += hv.x * a1.x + hv.y * a1.y + hv.z * a1.z + hv.w * a1.w;
        d2 += hv.x * a2.x + hv.y * a2.y + hv.z * a2.z + hv.w * a2.w;
    }
#pragma unroll
    for (int q = 0; q < 4; ++q) {
        const int f4 = q * 16 + scol;
        const float4 jv = ((const float4*)jrow)[f4];
        *(unsigned long long*)((char*)X + ((srow * 1024 + 512 + f4 * 8) ^ sswz)) =
            pk4(jv.x, jv.y, jv.z, jv.w);
    }
    d1 += __shfl_xor(d1, 1); d1 += __shfl_xor(d1, 2);
    d1 += __shfl_xor(d1, 4); d1 += __shfl_xor(d1, 8);
    d2 += __shfl_xor(d2, 1); d2 += __shfl_xor(d2, 2);
    d2 += __shfl_xor(d2, 4); d2 += __shfl_xor(d2, 8);
    if (scol == 0) { s1[row0 + srow] = d1; s2[row0 + srow] = d2; }
    __syncthreads();

    const unsigned short* wb = Wt + (size_t)(w * 32 + (lane & 15)) * 512 + ((lane >> 4) * 8);
    const int abase = (lane & 15) * 1024 + ((lane >> 4) * 16);
    const int aswz = (lane & 7) << 4;

    f32x4 acc0 = {0.f, 0.f, 0.f, 0.f}, acc1 = {0.f, 0.f, 0.f, 0.f};
#pragma unroll
    for (int ks = 0; ks < 16; ++ks) {
        const short8v af = *(const short8v*)((const char*)X + ((abase + ks * 64) ^ aswz));
        const short8v b0 = *(const short8v*)(wb + ks * 32);
        const short8v b1 = *(const short8v*)(wb + 16 * 512 + ks * 32);
        acc0 = __builtin_amdgcn_mfma_f32_16x16x32_bf16(af, b0, acc0, 0, 0, 0);
        acc1 = __builtin_amdgcn_mfma_f32_16x16x32_bf16(af, b1, acc1, 0, 0, 0);
    }

    const int nn = n0 + (lane >> 4) * 4;
    const size_t vbase = (size_t)b * 524288
                       + ((size_t)(nn >> 5) << 13)
                       + (((nn & 31) >> 3) << 4) + ((nn & 7) << 1);
#pragma unroll
    for (int f = 0; f < 2; ++f) {
        const f32x4 ac = f ? acc1 : acc0;
        const int o = w * 32 + f * 16 + (lane & 15);
        *(unsigned long long*)((char*)Vf + vbase + o * 64) = pk4(ac[0], ac[1], ac[2], ac[3]);
    }

    const int gstride = 1024 * 256;
    for (int g = blockIdx.x * 256 + t; g < (BATCH * NN * NN) / 16; g += gstride) {
        const int4* ap = (const int4*)(adj + (size_t)g * 16);
        const int4 x0 = ap[0], x1 = ap[1], x2 = ap[2], x3 = ap[3];
        unsigned m = 0;
        m |= (x0.x > 0) ? 1u : 0u;        m |= (x0.y > 0) ? 2u : 0u;
        m |= (x0.z > 0) ? 4u : 0u;        m |= (x0.w > 0) ? 8u : 0u;
        m |= (x1.x > 0) ? 16u : 0u;       m |= (x1.y > 0) ? 32u : 0u;
        m |= (x1.z > 0) ? 64u : 0u;       m |= (x1.w > 0) ? 128u : 0u;
        m |= (x2.x > 0) ? 256u : 0u;      m |= (x2.y > 0) ? 512u : 0u;
        m |= (x2.z > 0) ? 1024u : 0u;     m |= (x2.w > 0) ? 2048u : 0u;
        m |= (x3.x > 0) ? 4096u : 0u;     m |= (x3.y > 0) ? 8192u : 0u;
        m |= (x3.z > 0) ? 16384u : 0u;    m |= (x3.w > 0) ? 32768u : 0u;
        bits16[g] = (unsigned short)m;
    }
}

// ---------------------------------------------------------------------------
// Kernel 2: masked softmax + attention@V + ELU.  (unchanged r15, factorized P)
// MEASUREMENT ROUND: launched TWICE (idempotent) — Δdur vs r15 = t_attn(warm).
// ---------------------------------------------------------------------------
#define IBLK 32

__global__ __launch_bounds__(256, 3) void k_attn(
    const unsigned char* __restrict__ bits, const unsigned short* __restrict__ Vf,
    const float* __restrict__ s1g, const float* __restrict__ s2g,
    float* __restrict__ out)
{
    __shared__ __align__(16) char smem[33792];   // [e2 8K | f2 8K | bitw 8.32K] -> comb
    __shared__ float rs_lds[4][IBLK];
    __shared__ float wmaxs[4];
    __shared__ __align__(16) float lut[16][4];

    float* e2_lds = (float*)smem;                         // [0 : 8192)
    float* f2_lds = (float*)(smem + 8192);                // [8192 : 16384)
    unsigned int* bitw = (unsigned int*)(smem + 16384);   // [32][65] words, padded
    float* comb = (float*)smem;                           // after loop: [4][64][33]

    const int t = threadIdx.x, lane = t & 63, w = t >> 6;
    const int orig = blockIdx.x;
    const int b = orig & 7;
    const int r = orig >> 3;
    const int oh = r >> 6;              // o-half: cols oh*64 .. +63
    const int i0 = (r & 63) << 5;

    if (t < 16) {
        lut[t][0] = (float)(t & 1);
        lut[t][1] = (float)((t >> 1) & 1);
        lut[t][2] = (float)((t >> 2) & 1);
        lut[t][3] = (float)((t >> 3) & 1);
    }

    {
        const unsigned int* bg = (const unsigned int*)(bits + ((size_t)b * NN + i0) * 256);
#pragma unroll
        for (int q = 0; q < 8; ++q) {
            const int idx = q * 256 + t;   // 0..2047
            bitw[(idx >> 6) * 65 + (idx & 63)] = bg[idx];
        }
    }

    const float4* s2v = (const float4*)(s2g + b * NN);
    float lmax = -1e30f;
#pragma unroll
    for (int q = 0; q < 2; ++q) {
        const int idx = q * 256 + t;
        const float4 v = s2v[idx];
        ((float4*)e2_lds)[idx] = make_float4(__expf(v.x), __expf(v.y),
                                             __expf(v.z), __expf(v.w));
        ((float4*)f2_lds)[idx] = make_float4(__expf(ALPHA * v.x), __expf(ALPHA * v.y),
                                             __expf(ALPHA * v.z), __expf(ALPHA * v.w));
        lmax = fmaxf(fmaxf(lmax, fmaxf(v.x, v.y)), fmaxf(v.z, v.w));
    }
#pragma unroll
    for (int off = 32; off; off >>= 1) lmax = fmaxf(lmax, __shfl_xor(lmax, off));
    if (lane == 0) wmaxs[w] = lmax;

    const int irow = lane & 15;     // subtile-local row
    const int kcb = lane >> 4;      // k-strip 0..3 within a 32-k step
    const int kw = w * 512;         // this wave's k-range

    const float s1r0 = s1g[b * NN + i0 + irow];
    const float s1r1 = s1g[b * NN + i0 + 16 + irow];
    __syncthreads();
    const float s2max = fmaxf(fmaxf(wmaxs[0], wmaxs[1]), fmaxf(wmaxs[2], wmaxs[3]));
    const float mx0 = s1r0 + s2max, mx1 = s1r1 + s2max;
    const float mA0 = fmaxf(mx0, ALPHA * mx0);
    const float mA1 = fmaxf(mx1, ALPHA * mx1);
    const float c0 = __expf(s1r0 - mA0), d0 = __expf(ALPHA * s1r0 - mA0);
    const float c1 = __expf(s1r1 - mA1), d1 = __expf(ALPHA * s1r1 - mA1);

    const float* e2p = e2_lds + kw + kcb * 8;
    const float* f2p = f2_lds + kw + kcb * 8;
    const char* vfb = (const char*)Vf + (size_t)b * 524288 + (size_t)(w * 16) * 8192
                    + (size_t)(oh * 64 + irow) * 64 + (size_t)kcb * 16;
    const unsigned int* bw0p = bitw + irow * 65 + w * 16;
    const unsigned int* bw1p = bitw + (16 + irow) * 65 + w * 16;

    short8v vone;
#pragma unroll
    for (int q = 0; q < 8; ++q) vone[q] = (short)0x3F80;  // bf16 1.0

    f32x4 acc0[4], acc1[4];
    f32x4 acc_ps0 = {0.f, 0.f, 0.f, 0.f}, acc_ps1 = {0.f, 0.f, 0.f, 0.f};
#pragma unroll
    for (int og = 0; og < 4; ++og) {
        acc0[og] = (f32x4){0.f, 0.f, 0.f, 0.f};
        acc1[og] = (f32x4){0.f, 0.f, 0.f, 0.f};
    }

#pragma unroll
    for (int ks = 0; ks < 16; ++ks) {
        const char* vk = vfb + (size_t)ks * 8192;
        const short8v vf0 = *(const short8v*)(vk);
        const short8v vf1 = *(const short8v*)(vk + 1024);
        const short8v vf2 = *(const short8v*)(vk + 2048);
        const short8v vf3 = *(const short8v*)(vk + 3072);

        const unsigned int bb0 = (bw0p[ks] >> (kcb * 8)) & 0xffu;
        const unsigned int bb1 = (bw1p[ks] >> (kcb * 8)) & 0xffu;
        const float4 m00 = ((const float4*)lut)[bb0 & 15], m01 = ((const float4*)lut)[bb0 >> 4];
        const float4 m10 = ((const float4*)lut)[bb1 & 15], m11 = ((const float4*)lut)[bb1 >> 4];

        const float4 ea = *(const float4*)(e2p + ks * 32);
        const float4 eb = *(const float4*)(e2p + ks * 32 + 4);
        const float4 fa = *(const float4*)(f2p + ks * 32);
        const float4 fb = *(const float4*)(f2p + ks * 32 + 4);
        const float e2r[8] = {ea.x, ea.y, ea.z, ea.w, eb.x, eb.y, eb.z, eb.w};
        const float f2r[8] = {fa.x, fa.y, fa.z, fa.w, fb.x, fb.y, fb.z, fb.w};
        const float mk0[8] = {m00.x, m00.y, m00.z, m00.w, m01.x, m01.y, m01.z, m01.w};
        const float mk1[8] = {m10.x, m10.y, m10.z, m10.w, m11.x, m11.y, m11.z, m11.w};

        float p0[8], p1[8];
#pragma unroll
        for (int e = 0; e < 8; ++e) {
            p0[e] = fmaxf(c0 * e2r[e], d0 * f2r[e]) * mk0[e];
            p1[e] = fmaxf(c1 * e2r[e], d1 * f2r[e]) * mk1[e];
        }
        union { short8v v; __hip_bfloat162 h2[4]; } pb0, pb1;
#pragma unroll
        for (int q = 0; q < 4; ++q) {
            pb0.h2[q] = __float22bfloat162_rn(make_float2(p0[2 * q], p0[2 * q + 1]));
            pb1.h2[q] = __float22bfloat162_rn(make_float2(p1[2 * q], p1[2 * q + 1]));
        }

        acc_ps0 = __builtin_amdgcn_mfma_f32_16x16x32_bf16(vone, pb0.v, acc_ps0, 0, 0, 0);
        acc_ps1 = __builtin_amdgcn_mfma_f32_16x16x32_bf16(vone, pb1.v, acc_ps1, 0, 0, 0);
        acc0[0] = __builtin_amdgcn_mfma_f32_16x16x32_bf16(vf0, pb0.v, acc0[0], 0, 0, 0);
        acc1[0] = __builtin_amdgcn_mfma_f32_16x16x32_bf16(vf0, pb1.v, acc1[0], 0, 0, 0);
        acc0[1] = __builtin_amdgcn_mfma_f32_16x16x32_bf16(vf1, pb0.v, acc0[1], 0, 0, 0);
        acc1[1] = __builtin_amdgcn_mfma_f32_16x16x32_bf16(vf1, pb1.v, acc1[1], 0, 0, 0);
        acc0[2] = __builtin_amdgcn_mfma_f32_16x16x32_bf16(vf2, pb0.v, acc0[2], 0, 0, 0);
        acc1[2] = __builtin_amdgcn_mfma_f32_16x16x32_bf16(vf2, pb1.v, acc1[2], 0, 0, 0);
        acc0[3] = __builtin_amdgcn_mfma_f32_16x16x32_bf16(vf3, pb0.v, acc0[3], 0, 0, 0);
        acc1[3] = __builtin_amdgcn_mfma_f32_16x16x32_bf16(vf3, pb1.v, acc1[3], 0, 0, 0);
    }

    if (lane < 16) {
        rs_lds[w][lane] = acc_ps0[0];
        rs_lds[w][16 + lane] = acc_ps1[0];
    }

    __syncthreads();  // e2/f2/bitw dead; smem becomes comb
#pragma unroll
    for (int og = 0; og < 4; ++og) {
#pragma unroll
        for (int rr = 0; rr < 4; ++rr) {
            const int ol = og * 16 + kcb * 4 + rr;
            comb[(w * 64 + ol) * 33 + irow] = acc0[og][rr];
            comb[(w * 64 + ol) * 33 + 16 + irow] = acc1[og][rr];
        }
    }
    __syncthreads();

    const int i = t >> 3, oc = t & 7;
    const float tot = rs_lds[0][i] + rs_lds[1][i] + rs_lds[2][i] + rs_lds[3][i];
    const float inv = 1.0f / tot;
    float res[8];
#pragma unroll
    for (int u = 0; u < 8; ++u) {
        const int ol = oc * 8 + u;
        float v = comb[ol * 33 + i] + comb[(64 + ol) * 33 + i]
                + comb[(128 + ol) * 33 + i] + comb[(192 + ol) * 33 + i];
        v *= inv;
        res[u] = (v > 0.f) ? v : expm1f(v);
    }
    float4* ob = (float4*)(out + ((size_t)b * NN + i0 + i) * OUT_F + oh * 64 + oc * 8);
    ob[0] = make_float4(res[0], res[1], res[2], res[3]);
    ob[1] = make_float4(res[4], res[5], res[6], res[7]);
}

// ---------------------------------------------------------------------------
extern "C" void kernel_launch(void* const* d_in, const int* in_sizes, int n_in,
                              void* d_out, int out_size, void* d_ws, size_t ws_size,
                              hipStream_t stream) {
    const float* h  = (const float*)d_in[0];
    const float* j  = (const float*)d_in[1];
    const int* adj  = (const int*)d_in[2];
    const float* W1 = (const float*)d_in[3];
    const float* W2 = (const float*)d_in[4];
    const float* a  = (const float*)d_in[5];
    float* out = (float*)d_out;

    char* ws = (char*)d_ws;
    unsigned short* Vf = (unsigned short*)ws;               // 4 MB fragment-major
    ws += (size_t)BATCH * OUT_F * NN * 2;
    float* s1 = (float*)ws; ws += (size_t)BATCH * NN * 4;   // 64 KB
    float* s2 = (float*)ws; ws += (size_t)BATCH * NN * 4;   // 64 KB
    unsigned short* Wt = (unsigned short*)ws; ws += 128 * 512 * 2;  // 128 KB
    float* w1a1 = (float*)ws; ws += 512 * 4;
    float* w1a2 = (float*)ws; ws += 512 * 4;
    unsigned char* bits = (unsigned char*)ws;               // B*N*N/8 = 4 MB

    k_prew<<<64, 256, 0, stream>>>(W1, W2, a, Wt, w1a1, w1a2);
    k_proj<<<(BATCH * NN) / BM, 256, 0, stream>>>(h, j, Wt, w1a1, w1a2, adj,
                                                  Vf, s1, s2, (unsigned short*)bits);
    k_attn<<<(BATCH * NN) / IBLK * 2, 256, 0, stream>>>(bits, Vf, s1, s2, out);
    // MEASUREMENT: duplicate launch (idempotent). dur - 63.1 = t_attn(warm).
    k_attn<<<(BATCH * NN) / IBLK * 2, 256, 0, stream>>>(bits, Vf, s1, s2, out);
}

// Round 17
// 71.649 us; speedup vs baseline: 1.1721x; 1.1721x over previous
//
#include <hip/hip_runtime.h>
#include <hip/hip_bf16.h>

// Problem constants
#define BATCH 8
#define NN 2048
#define IN_F 256
#define OUT_F 128
#define ALPHA 0.2f

typedef __attribute__((ext_vector_type(8))) short short8v;
typedef __attribute__((ext_vector_type(4))) float f32x4;

// exact RTNE f32 -> bf16 bits (scalar)
static __device__ __forceinline__ unsigned short f2bf(float x) {
    unsigned int u = __float_as_uint(x);
    u = (u + 0x7fffu + ((u >> 16) & 1u)) >> 16;
    return (unsigned short)u;
}

// pack 4 floats -> 4 bf16 (8 B) via v_cvt_pk_bf16_f32 (RTNE, compiler-emitted)
static __device__ __forceinline__ unsigned long long pk4(float a, float b, float c, float d) {
    union { unsigned long long ll; __hip_bfloat162 h2[2]; } u;
    u.h2[0] = __float22bfloat162_rn(make_float2(a, b));
    u.h2[1] = __float22bfloat162_rn(make_float2(c, d));
    return u.ll;
}

// ---------------------------------------------------------------------------
// Kernel 0: weight prep.  (unchanged r15)
// ---------------------------------------------------------------------------
__global__ __launch_bounds__(256) void k_prew(
    const float* __restrict__ W1, const float* __restrict__ W2,
    const float* __restrict__ a,
    unsigned short* __restrict__ Wt, float* __restrict__ w1a1, float* __restrict__ w1a2)
{
    const int t = threadIdx.x;
    const int k8 = blockIdx.x * 8;
#pragma unroll
    for (int q = 0; q < 4; ++q) {
        const int idx = q * 256 + t;
        const int o = idx & 127;
        const int kk = k8 + (idx >> 7);
        const float v = (kk < IN_F) ? W1[kk * OUT_F + o] : W2[(kk - IN_F) * OUT_F + o];
        Wt[(size_t)o * 512 + kk] = f2bf(v);
    }
    if (k8 < IN_F) {
        const int lane = t & 63, w = t >> 6;
#pragma unroll
        for (int u = 0; u < 2; ++u) {
            const int kk = k8 + 2 * w + u;
            const float* wr = W1 + kk * OUT_F;
            float v1 = wr[lane] * a[lane] + wr[lane + 64] * a[lane + 64];
            float v2 = wr[lane] * a[OUT_F + lane] + wr[lane + 64] * a[OUT_F + lane + 64];
#pragma unroll
            for (int off = 32; off; off >>= 1) {
                v1 += __shfl_xor(v1, off);
                v2 += __shfl_xor(v2, off);
            }
            if (lane == 0) { w1a1[kk] = v1; w1a2[kk] = v2; }
        }
    }
}

// ---------------------------------------------------------------------------
// Kernel 1: projections via bf16 MFMA + strided adj->bits sweep tail.
// (unchanged r15 / r9 form)
// ---------------------------------------------------------------------------
#define BM 16

__global__ __launch_bounds__(256) void k_proj(
    const float* __restrict__ h, const float* __restrict__ j,
    const unsigned short* __restrict__ Wt,
    const float* __restrict__ w1a1g, const float* __restrict__ w1a2g,
    const int* __restrict__ adj,
    unsigned short* __restrict__ Vf, float* __restrict__ s1, float* __restrict__ s2,
    unsigned short* __restrict__ bits16)
{
    __shared__ __align__(16) unsigned short X[BM * 512];  // 16 KB, XOR-swizzled

    const int t = threadIdx.x, lane = t & 63, w = t >> 6;
    const int row0 = blockIdx.x * BM;
    const int b = row0 >> 11, n0 = row0 & 2047;

    const float4* wa1v = (const float4*)w1a1g;
    const float4* wa2v = (const float4*)w1a2g;

    const int srow = w * 4 + (lane >> 4);   // this lane's staging row (fixed)
    const int scol = lane & 15;
    const int sswz = (srow & 7) << 4;
    const float* hrow = h + (size_t)(row0 + srow) * IN_F;
    const float* jrow = j + (size_t)(row0 + srow) * IN_F;

    float d1 = 0.f, d2 = 0.f;
#pragma unroll
    for (int q = 0; q < 4; ++q) {
        const int f4 = q * 16 + scol;
        const float4 hv = ((const float4*)hrow)[f4];
        *(unsigned long long*)((char*)X + ((srow * 1024 + f4 * 8) ^ sswz)) =
            pk4(hv.x, hv.y, hv.z, hv.w);
        const float4 a1 = wa1v[f4], a2 = wa2v[f4];
        d1 += hv.x * a1.x + hv.y * a1.y + hv.z * a1.z + hv.w * a1.w;
        d2 += hv.x * a2.x + hv.y * a2.y + hv.z * a2.z + hv.w * a2.w;
    }
#pragma unroll
    for (int q = 0; q < 4; ++q) {
        const int f4 = q * 16 + scol;
        const float4 jv = ((const float4*)jrow)[f4];
        *(unsigned long long*)((char*)X + ((srow * 1024 + 512 + f4 * 8) ^ sswz)) =
            pk4(jv.x, jv.y, jv.z, jv.w);
    }
    d1 += __shfl_xor(d1, 1); d1 += __shfl_xor(d1, 2);
    d1 += __shfl_xor(d1, 4); d1 += __shfl_xor(d1, 8);
    d2 += __shfl_xor(d2, 1); d2 += __shfl_xor(d2, 2);
    d2 += __shfl_xor(d2, 4); d2 += __shfl_xor(d2, 8);
    if (scol == 0) { s1[row0 + srow] = d1; s2[row0 + srow] = d2; }
    __syncthreads();

    const unsigned short* wb = Wt + (size_t)(w * 32 + (lane & 15)) * 512 + ((lane >> 4) * 8);
    const int abase = (lane & 15) * 1024 + ((lane >> 4) * 16);
    const int aswz = (lane & 7) << 4;

    f32x4 acc0 = {0.f, 0.f, 0.f, 0.f}, acc1 = {0.f, 0.f, 0.f, 0.f};
#pragma unroll
    for (int ks = 0; ks < 16; ++ks) {
        const short8v af = *(const short8v*)((const char*)X + ((abase + ks * 64) ^ aswz));
        const short8v b0 = *(const short8v*)(wb + ks * 32);
        const short8v b1 = *(const short8v*)(wb + 16 * 512 + ks * 32);
        acc0 = __builtin_amdgcn_mfma_f32_16x16x32_bf16(af, b0, acc0, 0, 0, 0);
        acc1 = __builtin_amdgcn_mfma_f32_16x16x32_bf16(af, b1, acc1, 0, 0, 0);
    }

    const int nn = n0 + (lane >> 4) * 4;
    const size_t vbase = (size_t)b * 524288
                       + ((size_t)(nn >> 5) << 13)
                       + (((nn & 31) >> 3) << 4) + ((nn & 7) << 1);
#pragma unroll
    for (int f = 0; f < 2; ++f) {
        const f32x4 ac = f ? acc1 : acc0;
        const int o = w * 32 + f * 16 + (lane & 15);
        *(unsigned long long*)((char*)Vf + vbase + o * 64) = pk4(ac[0], ac[1], ac[2], ac[3]);
    }

    const int gstride = 1024 * 256;
    for (int g = blockIdx.x * 256 + t; g < (BATCH * NN * NN) / 16; g += gstride) {
        const int4* ap = (const int4*)(adj + (size_t)g * 16);
        const int4 x0 = ap[0], x1 = ap[1], x2 = ap[2], x3 = ap[3];
        unsigned m = 0;
        m |= (x0.x > 0) ? 1u : 0u;        m |= (x0.y > 0) ? 2u : 0u;
        m |= (x0.z > 0) ? 4u : 0u;        m |= (x0.w > 0) ? 8u : 0u;
        m |= (x1.x > 0) ? 16u : 0u;       m |= (x1.y > 0) ? 32u : 0u;
        m |= (x1.z > 0) ? 64u : 0u;       m |= (x1.w > 0) ? 128u : 0u;
        m |= (x2.x > 0) ? 256u : 0u;      m |= (x2.y > 0) ? 512u : 0u;
        m |= (x2.z > 0) ? 1024u : 0u;     m |= (x2.w > 0) ? 2048u : 0u;
        m |= (x3.x > 0) ? 4096u : 0u;     m |= (x3.y > 0) ? 8192u : 0u;
        m |= (x3.z > 0) ? 16384u : 0u;    m |= (x3.w > 0) ? 32768u : 0u;
        bits16[g] = (unsigned short)m;
    }
}

// ---------------------------------------------------------------------------
// Kernel 2: masked softmax + attention@V + ELU.  O-MERGED: one block = 32 rows
// x ALL 128 cols (grid 512, launch_bounds(256,2) — grid-capped at 2 blocks/CU
// so the higher VGPR cap is free).  vs r15: halves block prologues (bits/e2/f2
// staging+exp), halves epilogues, removes the duplicate P-computation, and
// doubles MFMA per P-pack (16 acc MFMAs fed by one P pair per step).
// Factorized P: max(c_i*e2[k], d_i*f2[k]) * mask  — no transcendentals in loop.
// ---------------------------------------------------------------------------
#define IBLK 32

__global__ __launch_bounds__(256, 2) void k_attn(
    const unsigned char* __restrict__ bits, const unsigned short* __restrict__ Vf,
    const float* __restrict__ s1g, const float* __restrict__ s2g,
    float* __restrict__ out)
{
    __shared__ __align__(16) char smem[34816];   // [e2 8K|f2 8K|bitw 8.32K] -> comb[4][128][17]
    __shared__ float rs_lds[4][IBLK];
    __shared__ float wmaxs[4];
    __shared__ __align__(16) float lut[16][4];

    float* e2_lds = (float*)smem;                         // [0 : 8192)
    float* f2_lds = (float*)(smem + 8192);                // [8192 : 16384)
    unsigned int* bitw = (unsigned int*)(smem + 16384);   // [32][65] words, padded
    float* comb = (float*)smem;                           // after loop: [4][128][17]

    const int t = threadIdx.x, lane = t & 63, w = t >> 6;
    // grid 512 = 8 batches x 64 row-tiles; batch = XCD
    const int orig = blockIdx.x;
    const int b = orig & 7;
    const int i0 = (orig >> 3) << 5;

    if (t < 16) {
        lut[t][0] = (float)(t & 1);
        lut[t][1] = (float)((t >> 1) & 1);
        lut[t][2] = (float)((t >> 2) & 1);
        lut[t][3] = (float)((t >> 3) & 1);
    }

    // ---- stage bits: 32 rows x 64 words -> padded stride 65 (bank-clean) ----
    {
        const unsigned int* bg = (const unsigned int*)(bits + ((size_t)b * NN + i0) * 256);
#pragma unroll
        for (int q = 0; q < 8; ++q) {
            const int idx = q * 256 + t;   // 0..2047
            bitw[(idx >> 6) * 65 + (idx & 63)] = bg[idx];
        }
    }

    // ---- stage e2 = exp(s2), f2 = exp(0.2*s2) + global s2 max ----
    const float4* s2v = (const float4*)(s2g + b * NN);
    float lmax = -1e30f;
#pragma unroll
    for (int q = 0; q < 2; ++q) {
        const int idx = q * 256 + t;
        const float4 v = s2v[idx];
        ((float4*)e2_lds)[idx] = make_float4(__expf(v.x), __expf(v.y),
                                             __expf(v.z), __expf(v.w));
        ((float4*)f2_lds)[idx] = make_float4(__expf(ALPHA * v.x), __expf(ALPHA * v.y),
                                             __expf(ALPHA * v.z), __expf(ALPHA * v.w));
        lmax = fmaxf(fmaxf(lmax, fmaxf(v.x, v.y)), fmaxf(v.z, v.w));
    }
#pragma unroll
    for (int off = 32; off; off >>= 1) lmax = fmaxf(lmax, __shfl_xor(lmax, off));
    if (lane == 0) wmaxs[w] = lmax;

    const int irow = lane & 15;     // subtile-local row
    const int kcb = lane >> 4;      // k-strip 0..3 within a 32-k step
    const int kw = w * 512;         // this wave's k-range

    const float s1r0 = s1g[b * NN + i0 + irow];
    const float s1r1 = s1g[b * NN + i0 + 16 + irow];
    __syncthreads();
    const float s2max = fmaxf(fmaxf(wmaxs[0], wmaxs[1]), fmaxf(wmaxs[2], wmaxs[3]));
    const float mx0 = s1r0 + s2max, mx1 = s1r1 + s2max;
    const float mA0 = fmaxf(mx0, ALPHA * mx0);
    const float mA1 = fmaxf(mx1, ALPHA * mx1);
    const float c0 = __expf(s1r0 - mA0), d0 = __expf(ALPHA * s1r0 - mA0);
    const float c1 = __expf(s1r1 - mA1), d1 = __expf(ALPHA * s1r1 - mA1);

    const float* e2p = e2_lds + kw + kcb * 8;
    const float* f2p = f2_lds + kw + kcb * 8;
    // Vf base: this wave's k-blocks start at w*16; lane offset irow*64 + kcb*16.
    // Per step, og-th load (o-cols og*16..+15) at +og*1024 -> dense 1 KB each.
    const char* vfb = (const char*)Vf + (size_t)b * 524288 + (size_t)(w * 16) * 8192
                    + (size_t)irow * 64 + (size_t)kcb * 16;
    const unsigned int* bw0p = bitw + irow * 65 + w * 16;
    const unsigned int* bw1p = bitw + (16 + irow) * 65 + w * 16;

    short8v vone;
#pragma unroll
    for (int q = 0; q < 8; ++q) vone[q] = (short)0x3F80;  // bf16 1.0

    f32x4 acc0[8], acc1[8];
    f32x4 ps0 = {0.f, 0.f, 0.f, 0.f}, ps1 = {0.f, 0.f, 0.f, 0.f};
#pragma unroll
    for (int og = 0; og < 8; ++og) {
        acc0[og] = (f32x4){0.f, 0.f, 0.f, 0.f};
        acc1[og] = (f32x4){0.f, 0.f, 0.f, 0.f};
    }

#pragma unroll
    for (int ks = 0; ks < 16; ++ks) {
        // 8 dense 1 KB V loads covering all 128 o-cols of this k-step
        const char* vk = vfb + (size_t)ks * 8192;
        short8v vf[8];
#pragma unroll
        for (int og = 0; og < 8; ++og)
            vf[og] = *(const short8v*)(vk + og * 1024);

        const unsigned int bb0 = (bw0p[ks] >> (kcb * 8)) & 0xffu;
        const unsigned int bb1 = (bw1p[ks] >> (kcb * 8)) & 0xffu;
        const float4 m00 = ((const float4*)lut)[bb0 & 15], m01 = ((const float4*)lut)[bb0 >> 4];
        const float4 m10 = ((const float4*)lut)[bb1 & 15], m11 = ((const float4*)lut)[bb1 >> 4];

        const float4 ea = *(const float4*)(e2p + ks * 32);
        const float4 eb = *(const float4*)(e2p + ks * 32 + 4);
        const float4 fa = *(const float4*)(f2p + ks * 32);
        const float4 fb = *(const float4*)(f2p + ks * 32 + 4);
        const float e2r[8] = {ea.x, ea.y, ea.z, ea.w, eb.x, eb.y, eb.z, eb.w};
        const float f2r[8] = {fa.x, fa.y, fa.z, fa.w, fb.x, fb.y, fb.z, fb.w};
        const float mk0[8] = {m00.x, m00.y, m00.z, m00.w, m01.x, m01.y, m01.z, m01.w};
        const float mk1[8] = {m10.x, m10.y, m10.z, m10.w, m11.x, m11.y, m11.z, m11.w};

        float p0[8], p1[8];
#pragma unroll
        for (int e = 0; e < 8; ++e) {
            p0[e] = fmaxf(c0 * e2r[e], d0 * f2r[e]) * mk0[e];
            p1[e] = fmaxf(c1 * e2r[e], d1 * f2r[e]) * mk1[e];
        }
        union { short8v v; __hip_bfloat162 h2[4]; } pb0, pb1;
#pragma unroll
        for (int q = 0; q < 4; ++q) {
            pb0.h2[q] = __float22bfloat162_rn(make_float2(p0[2 * q], p0[2 * q + 1]));
            pb1.h2[q] = __float22bfloat162_rn(make_float2(p1[2 * q], p1[2 * q + 1]));
        }

        ps0 = __builtin_amdgcn_mfma_f32_16x16x32_bf16(vone, pb0.v, ps0, 0, 0, 0);
        ps1 = __builtin_amdgcn_mfma_f32_16x16x32_bf16(vone, pb1.v, ps1, 0, 0, 0);
#pragma unroll
        for (int og = 0; og < 8; ++og) {
            acc0[og] = __builtin_amdgcn_mfma_f32_16x16x32_bf16(vf[og], pb0.v, acc0[og], 0, 0, 0);
            acc1[og] = __builtin_amdgcn_mfma_f32_16x16x32_bf16(vf[og], pb1.v, acc1[og], 0, 0, 0);
        }
    }

    // ---- wave-partial row sums ----
    if (lane < 16) {
        rs_lds[w][lane] = ps0[0];
        rs_lds[w][16 + lane] = ps1[0];
    }

    __syncthreads();  // e2/f2/bitw dead; smem becomes comb [4][128][17]

    // ---- round A: row-subtile 0 (rows i0 .. i0+15) ----
#pragma unroll
    for (int og = 0; og < 8; ++og)
#pragma unroll
        for (int rr = 0; rr < 4; ++rr)
            comb[(w * 128 + og * 16 + kcb * 4 + rr) * 17 + irow] = acc0[og][rr];
    __syncthreads();
    {
        const int i = t >> 4, oc = t & 15;
        const float tot = rs_lds[0][i] + rs_lds[1][i] + rs_lds[2][i] + rs_lds[3][i];
        const float inv = 1.0f / tot;
        float res[8];
#pragma unroll
        for (int u = 0; u < 8; ++u) {
            const int ol = oc * 8 + u;
            float v = comb[ol * 17 + i] + comb[(128 + ol) * 17 + i]
                    + comb[(256 + ol) * 17 + i] + comb[(384 + ol) * 17 + i];
            v *= inv;
            res[u] = (v > 0.f) ? v : expm1f(v);
        }
        float4* ob = (float4*)(out + ((size_t)b * NN + i0 + i) * OUT_F + oc * 8);
        ob[0] = make_float4(res[0], res[1], res[2], res[3]);
        ob[1] = make_float4(res[4], res[5], res[6], res[7]);
    }
    __syncthreads();

    // ---- round B: row-subtile 1 (rows i0+16 .. i0+31) ----
#pragma unroll
    for (int og = 0; og < 8; ++og)
#pragma unroll
        for (int rr = 0; rr < 4; ++rr)
            comb[(w * 128 + og * 16 + kcb * 4 + rr) * 17 + irow] = acc1[og][rr];
    __syncthreads();
    {
        const int i = t >> 4, oc = t & 15;
        const float tot = rs_lds[0][16 + i] + rs_lds[1][16 + i]
                        + rs_lds[2][16 + i] + rs_lds[3][16 + i];
        const float inv = 1.0f / tot;
        float res[8];
#pragma unroll
        for (int u = 0; u < 8; ++u) {
            const int ol = oc * 8 + u;
            float v = comb[ol * 17 + i] + comb[(128 + ol) * 17 + i]
                    + comb[(256 + ol) * 17 + i] + comb[(384 + ol) * 17 + i];
            v *= inv;
            res[u] = (v > 0.f) ? v : expm1f(v);
        }
        float4* ob = (float4*)(out + ((size_t)b * NN + i0 + 16 + i) * OUT_F + oc * 8);
        ob[0] = make_float4(res[0], res[1], res[2], res[3]);
        ob[1] = make_float4(res[4], res[5], res[6], res[7]);
    }
}

// ---------------------------------------------------------------------------
extern "C" void kernel_launch(void* const* d_in, const int* in_sizes, int n_in,
                              void* d_out, int out_size, void* d_ws, size_t ws_size,
                              hipStream_t stream) {
    const float* h  = (const float*)d_in[0];
    const float* j  = (const float*)d_in[1];
    const int* adj  = (const int*)d_in[2];
    const float* W1 = (const float*)d_in[3];
    const float* W2 = (const float*)d_in[4];
    const float* a  = (const float*)d_in[5];
    float* out = (float*)d_out;

    char* ws = (char*)d_ws;
    unsigned short* Vf = (unsigned short*)ws;               // 4 MB fragment-major
    ws += (size_t)BATCH * OUT_F * NN * 2;
    float* s1 = (float*)ws; ws += (size_t)BATCH * NN * 4;   // 64 KB
    float* s2 = (float*)ws; ws += (size_t)BATCH * NN * 4;   // 64 KB
    unsigned short* Wt = (unsigned short*)ws; ws += 128 * 512 * 2;  // 128 KB
    float* w1a1 = (float*)ws; ws += 512 * 4;
    float* w1a2 = (float*)ws; ws += 512 * 4;
    unsigned char* bits = (unsigned char*)ws;               // B*N*N/8 = 4 MB

    k_prew<<<64, 256, 0, stream>>>(W1, W2, a, Wt, w1a1, w1a2);
    k_proj<<<(BATCH * NN) / BM, 256, 0, stream>>>(h, j, Wt, w1a1, w1a2, adj,
                                                  Vf, s1, s2, (unsigned short*)bits);
    k_attn<<<(BATCH * NN) / IBLK, 256, 0, stream>>>(bits, Vf, s1, s2, out);
}

// Round 18
// 62.786 us; speedup vs baseline: 1.3376x; 1.1412x over previous
//
#include <hip/hip_runtime.h>
#include <hip/hip_bf16.h>

// Problem constants
#define BATCH 8
#define NN 2048
#define IN_F 256
#define OUT_F 128
#define ALPHA 0.2f

typedef __attribute__((ext_vector_type(8))) short short8v;
typedef __attribute__((ext_vector_type(4))) float f32x4;

// exact RTNE f32 -> bf16 bits (scalar)
static __device__ __forceinline__ unsigned short f2bf(float x) {
    unsigned int u = __float_as_uint(x);
    u = (u + 0x7fffu + ((u >> 16) & 1u)) >> 16;
    return (unsigned short)u;
}

// pack 4 floats -> 4 bf16 (8 B) via v_cvt_pk_bf16_f32 (RTNE, compiler-emitted)
static __device__ __forceinline__ unsigned long long pk4(float a, float b, float c, float d) {
    union { unsigned long long ll; __hip_bfloat162 h2[2]; } u;
    u.h2[0] = __float22bfloat162_rn(make_float2(a, b));
    u.h2[1] = __float22bfloat162_rn(make_float2(c, d));
    return u.ll;
}

// ---------------------------------------------------------------------------
// Kernel 0: weight prep.  (unchanged r15)
// ---------------------------------------------------------------------------
__global__ __launch_bounds__(256) void k_prew(
    const float* __restrict__ W1, const float* __restrict__ W2,
    const float* __restrict__ a,
    unsigned short* __restrict__ Wt, float* __restrict__ w1a1, float* __restrict__ w1a2)
{
    const int t = threadIdx.x;
    const int k8 = blockIdx.x * 8;
#pragma unroll
    for (int q = 0; q < 4; ++q) {
        const int idx = q * 256 + t;
        const int o = idx & 127;
        const int kk = k8 + (idx >> 7);
        const float v = (kk < IN_F) ? W1[kk * OUT_F + o] : W2[(kk - IN_F) * OUT_F + o];
        Wt[(size_t)o * 512 + kk] = f2bf(v);
    }
    if (k8 < IN_F) {
        const int lane = t & 63, w = t >> 6;
#pragma unroll
        for (int u = 0; u < 2; ++u) {
            const int kk = k8 + 2 * w + u;
            const float* wr = W1 + kk * OUT_F;
            float v1 = wr[lane] * a[lane] + wr[lane + 64] * a[lane + 64];
            float v2 = wr[lane] * a[OUT_F + lane] + wr[lane + 64] * a[OUT_F + lane + 64];
#pragma unroll
            for (int off = 32; off; off >>= 1) {
                v1 += __shfl_xor(v1, off);
                v2 += __shfl_xor(v2, off);
            }
            if (lane == 0) { w1a1[kk] = v1; w1a2[kk] = v2; }
        }
    }
}

// ---------------------------------------------------------------------------
// Kernel 1: projections via bf16 MFMA + strided adj->bits sweep tail.
// (unchanged r15 / r9 form)
// ---------------------------------------------------------------------------
#define BM 16

__global__ __launch_bounds__(256) void k_proj(
    const float* __restrict__ h, const float* __restrict__ j,
    const unsigned short* __restrict__ Wt,
    const float* __restrict__ w1a1g, const float* __restrict__ w1a2g,
    const int* __restrict__ adj,
    unsigned short* __restrict__ Vf, float* __restrict__ s1, float* __restrict__ s2,
    unsigned short* __restrict__ bits16)
{
    __shared__ __align__(16) unsigned short X[BM * 512];  // 16 KB, XOR-swizzled

    const int t = threadIdx.x, lane = t & 63, w = t >> 6;
    const int row0 = blockIdx.x * BM;
    const int b = row0 >> 11, n0 = row0 & 2047;

    const float4* wa1v = (const float4*)w1a1g;
    const float4* wa2v = (const float4*)w1a2g;

    const int srow = w * 4 + (lane >> 4);   // this lane's staging row (fixed)
    const int scol = lane & 15;
    const int sswz = (srow & 7) << 4;
    const float* hrow = h + (size_t)(row0 + srow) * IN_F;
    const float* jrow = j + (size_t)(row0 + srow) * IN_F;

    float d1 = 0.f, d2 = 0.f;
#pragma unroll
    for (int q = 0; q < 4; ++q) {
        const int f4 = q * 16 + scol;
        const float4 hv = ((const float4*)hrow)[f4];
        *(unsigned long long*)((char*)X + ((srow * 1024 + f4 * 8) ^ sswz)) =
            pk4(hv.x, hv.y, hv.z, hv.w);
        const float4 a1 = wa1v[f4], a2 = wa2v[f4];
        d1 += hv.x * a1.x + hv.y * a1.y + hv.z * a1.z + hv.w * a1.w;
        d2 += hv.x * a2.x + hv.y * a2.y + hv.z * a2.z + hv.w * a2.w;
    }
#pragma unroll
    for (int q = 0; q < 4; ++q) {
        const int f4 = q * 16 + scol;
        const float4 jv = ((const float4*)jrow)[f4];
        *(unsigned long long*)((char*)X + ((srow * 1024 + 512 + f4 * 8) ^ sswz)) =
            pk4(jv.x, jv.y, jv.z, jv.w);
    }
    d1 += __shfl_xor(d1, 1); d1 += __shfl_xor(d1, 2);
    d1 += __shfl_xor(d1, 4); d1 += __shfl_xor(d1, 8);
    d2 += __shfl_xor(d2, 1); d2 += __shfl_xor(d2, 2);
    d2 += __shfl_xor(d2, 4); d2 += __shfl_xor(d2, 8);
    if (scol == 0) { s1[row0 + srow] = d1; s2[row0 + srow] = d2; }
    __syncthreads();

    const unsigned short* wb = Wt + (size_t)(w * 32 + (lane & 15)) * 512 + ((lane >> 4) * 8);
    const int abase = (lane & 15) * 1024 + ((lane >> 4) * 16);
    const int aswz = (lane & 7) << 4;

    f32x4 acc0 = {0.f, 0.f, 0.f, 0.f}, acc1 = {0.f, 0.f, 0.f, 0.f};
#pragma unroll
    for (int ks = 0; ks < 16; ++ks) {
        const short8v af = *(const short8v*)((const char*)X + ((abase + ks * 64) ^ aswz));
        const short8v b0 = *(const short8v*)(wb + ks * 32);
        const short8v b1 = *(const short8v*)(wb + 16 * 512 + ks * 32);
        acc0 = __builtin_amdgcn_mfma_f32_16x16x32_bf16(af, b0, acc0, 0, 0, 0);
        acc1 = __builtin_amdgcn_mfma_f32_16x16x32_bf16(af, b1, acc1, 0, 0, 0);
    }

    const int nn = n0 + (lane >> 4) * 4;
    const size_t vbase = (size_t)b * 524288
                       + ((size_t)(nn >> 5) << 13)
                       + (((nn & 31) >> 3) << 4) + ((nn & 7) << 1);
#pragma unroll
    for (int f = 0; f < 2; ++f) {
        const f32x4 ac = f ? acc1 : acc0;
        const int o = w * 32 + f * 16 + (lane & 15);
        *(unsigned long long*)((char*)Vf + vbase + o * 64) = pk4(ac[0], ac[1], ac[2], ac[3]);
    }

    const int gstride = 1024 * 256;
    for (int g = blockIdx.x * 256 + t; g < (BATCH * NN * NN) / 16; g += gstride) {
        const int4* ap = (const int4*)(adj + (size_t)g * 16);
        const int4 x0 = ap[0], x1 = ap[1], x2 = ap[2], x3 = ap[3];
        unsigned m = 0;
        m |= (x0.x > 0) ? 1u : 0u;        m |= (x0.y > 0) ? 2u : 0u;
        m |= (x0.z > 0) ? 4u : 0u;        m |= (x0.w > 0) ? 8u : 0u;
        m |= (x1.x > 0) ? 16u : 0u;       m |= (x1.y > 0) ? 32u : 0u;
        m |= (x1.z > 0) ? 64u : 0u;       m |= (x1.w > 0) ? 128u : 0u;
        m |= (x2.x > 0) ? 256u : 0u;      m |= (x2.y > 0) ? 512u : 0u;
        m |= (x2.z > 0) ? 1024u : 0u;     m |= (x2.w > 0) ? 2048u : 0u;
        m |= (x3.x > 0) ? 4096u : 0u;     m |= (x3.y > 0) ? 8192u : 0u;
        m |= (x3.z > 0) ? 16384u : 0u;    m |= (x3.w > 0) ? 32768u : 0u;
        bits16[g] = (unsigned short)m;
    }
}

// ---------------------------------------------------------------------------
// Kernel 2: masked softmax + attention@V + ELU.  (r15 skeleton, IBLK=32,
// o-split 64, k-split 4, grid 1024)
// CHANGES vs r15 (single lever: occupancy): launch_bounds(256,4) -> 4
// blocks/CU (LDS 4x34.8 = 139 KB < 160), 16 waves/CU vs 12. To fit the
// 128-VGPR cap, psum now accumulates via VALU adds (drops vone + ps MFMA:
// -16 VGPR, -2 MFMA/step) with a 3-step shfl reduce at the end.
// Factorized P: max(c_i*e2[k], d_i*f2[k]) * mask  — no transcendentals.
// ---------------------------------------------------------------------------
#define IBLK 32

__global__ __launch_bounds__(256, 4) void k_attn(
    const unsigned char* __restrict__ bits, const unsigned short* __restrict__ Vf,
    const float* __restrict__ s1g, const float* __restrict__ s2g,
    float* __restrict__ out)
{
    __shared__ __align__(16) char smem[33792];   // [e2 8K | f2 8K | bitw 8.32K] -> comb
    __shared__ float rs_lds[4][IBLK];
    __shared__ float wmaxs[4];
    __shared__ __align__(16) float lut[16][4];

    float* e2_lds = (float*)smem;                         // [0 : 8192)
    float* f2_lds = (float*)(smem + 8192);                // [8192 : 16384)
    unsigned int* bitw = (unsigned int*)(smem + 16384);   // [32][65] words, padded
    float* comb = (float*)smem;                           // after loop: [4][64][33]

    const int t = threadIdx.x, lane = t & 63, w = t >> 6;
    const int orig = blockIdx.x;
    const int b = orig & 7;
    const int r = orig >> 3;
    const int oh = r >> 6;              // o-half: cols oh*64 .. +63
    const int i0 = (r & 63) << 5;

    if (t < 16) {
        lut[t][0] = (float)(t & 1);
        lut[t][1] = (float)((t >> 1) & 1);
        lut[t][2] = (float)((t >> 2) & 1);
        lut[t][3] = (float)((t >> 3) & 1);
    }

    // ---- stage bits: 32 rows x 64 words -> padded stride 65 (bank-clean) ----
    {
        const unsigned int* bg = (const unsigned int*)(bits + ((size_t)b * NN + i0) * 256);
#pragma unroll
        for (int q = 0; q < 8; ++q) {
            const int idx = q * 256 + t;   // 0..2047
            bitw[(idx >> 6) * 65 + (idx & 63)] = bg[idx];
        }
    }

    // ---- stage e2 = exp(s2), f2 = exp(0.2*s2) + global s2 max ----
    const float4* s2v = (const float4*)(s2g + b * NN);
    float lmax = -1e30f;
#pragma unroll
    for (int q = 0; q < 2; ++q) {
        const int idx = q * 256 + t;
        const float4 v = s2v[idx];
        ((float4*)e2_lds)[idx] = make_float4(__expf(v.x), __expf(v.y),
                                             __expf(v.z), __expf(v.w));
        ((float4*)f2_lds)[idx] = make_float4(__expf(ALPHA * v.x), __expf(ALPHA * v.y),
                                             __expf(ALPHA * v.z), __expf(ALPHA * v.w));
        lmax = fmaxf(fmaxf(lmax, fmaxf(v.x, v.y)), fmaxf(v.z, v.w));
    }
#pragma unroll
    for (int off = 32; off; off >>= 1) lmax = fmaxf(lmax, __shfl_xor(lmax, off));
    if (lane == 0) wmaxs[w] = lmax;

    const int irow = lane & 15;     // subtile-local row
    const int kcb = lane >> 4;      // k-strip 0..3 within a 32-k step
    const int kw = w * 512;         // this wave's k-range

    const float s1r0 = s1g[b * NN + i0 + irow];
    const float s1r1 = s1g[b * NN + i0 + 16 + irow];
    __syncthreads();
    const float s2max = fmaxf(fmaxf(wmaxs[0], wmaxs[1]), fmaxf(wmaxs[2], wmaxs[3]));
    const float mx0 = s1r0 + s2max, mx1 = s1r1 + s2max;
    const float mA0 = fmaxf(mx0, ALPHA * mx0);
    const float mA1 = fmaxf(mx1, ALPHA * mx1);
    const float c0 = __expf(s1r0 - mA0), d0 = __expf(ALPHA * s1r0 - mA0);
    const float c1 = __expf(s1r1 - mA1), d1 = __expf(ALPHA * s1r1 - mA1);

    const float* e2p = e2_lds + kw + kcb * 8;
    const float* f2p = f2_lds + kw + kcb * 8;
    const char* vfb = (const char*)Vf + (size_t)b * 524288 + (size_t)(w * 16) * 8192
                    + (size_t)(oh * 64 + irow) * 64 + (size_t)kcb * 16;
    const unsigned int* bw0p = bitw + irow * 65 + w * 16;
    const unsigned int* bw1p = bitw + (16 + irow) * 65 + w * 16;

    f32x4 acc0[4], acc1[4];
    float psum0 = 0.f, psum1 = 0.f;
#pragma unroll
    for (int og = 0; og < 4; ++og) {
        acc0[og] = (f32x4){0.f, 0.f, 0.f, 0.f};
        acc1[og] = (f32x4){0.f, 0.f, 0.f, 0.f};
    }

#pragma unroll
    for (int ks = 0; ks < 16; ++ks) {
        // V fragments: dense 1 KB loads (loads first: P-compute covers latency)
        const char* vk = vfb + (size_t)ks * 8192;
        const short8v vf0 = *(const short8v*)(vk);
        const short8v vf1 = *(const short8v*)(vk + 1024);
        const short8v vf2 = *(const short8v*)(vk + 2048);
        const short8v vf3 = *(const short8v*)(vk + 3072);

        const unsigned int bb0 = (bw0p[ks] >> (kcb * 8)) & 0xffu;
        const unsigned int bb1 = (bw1p[ks] >> (kcb * 8)) & 0xffu;
        const float4 m00 = ((const float4*)lut)[bb0 & 15], m01 = ((const float4*)lut)[bb0 >> 4];
        const float4 m10 = ((const float4*)lut)[bb1 & 15], m11 = ((const float4*)lut)[bb1 >> 4];

        const float4 ea = *(const float4*)(e2p + ks * 32);
        const float4 eb = *(const float4*)(e2p + ks * 32 + 4);
        const float4 fa = *(const float4*)(f2p + ks * 32);
        const float4 fb = *(const float4*)(f2p + ks * 32 + 4);
        const float e2r[8] = {ea.x, ea.y, ea.z, ea.w, eb.x, eb.y, eb.z, eb.w};
        const float f2r[8] = {fa.x, fa.y, fa.z, fa.w, fb.x, fb.y, fb.z, fb.w};
        const float mk0[8] = {m00.x, m00.y, m00.z, m00.w, m01.x, m01.y, m01.z, m01.w};
        const float mk1[8] = {m10.x, m10.y, m10.z, m10.w, m11.x, m11.y, m11.z, m11.w};

        float p0[8], p1[8];
#pragma unroll
        for (int e = 0; e < 8; ++e) {
            p0[e] = fmaxf(c0 * e2r[e], d0 * f2r[e]) * mk0[e];
            p1[e] = fmaxf(c1 * e2r[e], d1 * f2r[e]) * mk1[e];
            psum0 += p0[e];
            psum1 += p1[e];
        }
        union { short8v v; __hip_bfloat162 h2[4]; } pb0, pb1;
#pragma unroll
        for (int q = 0; q < 4; ++q) {
            pb0.h2[q] = __float22bfloat162_rn(make_float2(p0[2 * q], p0[2 * q + 1]));
            pb1.h2[q] = __float22bfloat162_rn(make_float2(p1[2 * q], p1[2 * q + 1]));
        }

        acc0[0] = __builtin_amdgcn_mfma_f32_16x16x32_bf16(vf0, pb0.v, acc0[0], 0, 0, 0);
        acc1[0] = __builtin_amdgcn_mfma_f32_16x16x32_bf16(vf0, pb1.v, acc1[0], 0, 0, 0);
        acc0[1] = __builtin_amdgcn_mfma_f32_16x16x32_bf16(vf1, pb0.v, acc0[1], 0, 0, 0);
        acc1[1] = __builtin_amdgcn_mfma_f32_16x16x32_bf16(vf1, pb1.v, acc1[1], 0, 0, 0);
        acc0[2] = __builtin_amdgcn_mfma_f32_16x16x32_bf16(vf2, pb0.v, acc0[2], 0, 0, 0);
        acc1[2] = __builtin_amdgcn_mfma_f32_16x16x32_bf16(vf2, pb1.v, acc1[2], 0, 0, 0);
        acc0[3] = __builtin_amdgcn_mfma_f32_16x16x32_bf16(vf3, pb0.v, acc0[3], 0, 0, 0);
        acc1[3] = __builtin_amdgcn_mfma_f32_16x16x32_bf16(vf3, pb1.v, acc1[3], 0, 0, 0);
    }

    // ---- row sums: psum is per (row, k-strip); reduce over the 4 k-strips.
    // Lanes irow, irow+16, irow+32, irow+48 hold the same row's partials.
    psum0 += __shfl_xor(psum0, 16);
    psum0 += __shfl_xor(psum0, 32);
    psum1 += __shfl_xor(psum1, 16);
    psum1 += __shfl_xor(psum1, 32);
    if (lane < 16) {
        rs_lds[w][lane] = psum0;
        rs_lds[w][16 + lane] = psum1;
    }

    __syncthreads();  // e2/f2/bitw dead; smem becomes comb
#pragma unroll
    for (int og = 0; og < 4; ++og) {
#pragma unroll
        for (int rr = 0; rr < 4; ++rr) {
            const int ol = og * 16 + kcb * 4 + rr;
            comb[(w * 64 + ol) * 33 + irow] = acc0[og][rr];
            comb[(w * 64 + ol) * 33 + 16 + irow] = acc1[og][rr];
        }
    }
    __syncthreads();

    const int i = t >> 3, oc = t & 7;
    const float tot = rs_lds[0][i] + rs_lds[1][i] + rs_lds[2][i] + rs_lds[3][i];
    const float inv = 1.0f / tot;
    float res[8];
#pragma unroll
    for (int u = 0; u < 8; ++u) {
        const int ol = oc * 8 + u;
        float v = comb[ol * 33 + i] + comb[(64 + ol) * 33 + i]
                + comb[(128 + ol) * 33 + i] + comb[(192 + ol) * 33 + i];
        v *= inv;
        res[u] = (v > 0.f) ? v : expm1f(v);
    }
    float4* ob = (float4*)(out + ((size_t)b * NN + i0 + i) * OUT_F + oh * 64 + oc * 8);
    ob[0] = make_float4(res[0], res[1], res[2], res[3]);
    ob[1] = make_float4(res[4], res[5], res[6], res[7]);
}

// ---------------------------------------------------------------------------
extern "C" void kernel_launch(void* const* d_in, const int* in_sizes, int n_in,
                              void* d_out, int out_size, void* d_ws, size_t ws_size,
                              hipStream_t stream) {
    const float* h  = (const float*)d_in[0];
    const float* j  = (const float*)d_in[1];
    const int* adj  = (const int*)d_in[2];
    const float* W1 = (const float*)d_in[3];
    const float* W2 = (const float*)d_in[4];
    const float* a  = (const float*)d_in[5];
    float* out = (float*)d_out;

    char* ws = (char*)d_ws;
    unsigned short* Vf = (unsigned short*)ws;               // 4 MB fragment-major
    ws += (size_t)BATCH * OUT_F * NN * 2;
    float* s1 = (float*)ws; ws += (size_t)BATCH * NN * 4;   // 64 KB
    float* s2 = (float*)ws; ws += (size_t)BATCH * NN * 4;   // 64 KB
    unsigned short* Wt = (unsigned short*)ws; ws += 128 * 512 * 2;  // 128 KB
    float* w1a1 = (float*)ws; ws += 512 * 4;
    float* w1a2 = (float*)ws; ws += 512 * 4;
    unsigned char* bits = (unsigned char*)ws;               // B*N*N/8 = 4 MB

    k_prew<<<64, 256, 0, stream>>>(W1, W2, a, Wt, w1a1, w1a2);
    k_proj<<<(BATCH * NN) / BM, 256, 0, stream>>>(h, j, Wt, w1a1, w1a2, adj,
                                                  Vf, s1, s2, (unsigned short*)bits);
    k_attn<<<(BATCH * NN) / IBLK * 2, 256, 0, stream>>>(bits, Vf, s1, s2, out);
}